// Round 8
// baseline (226.785 us; speedup 1.0000x reference)
//
#include <hip/hip_runtime.h>
#include <math.h>

#define GH 300
#define GW 400
#define GHW (GH * GW)

// Tile grid: 16x16 cells per tile
#define TCOLS 25                 // 400/16
#define TROWS 19                 // ceil(300/16)
#define T_TILES (TCOLS * TROWS)  // 475
#define B1 512                   // P1 blocks
#define Q 32                     // per-thread LDS record quota (per_block <= 8192)
#define MAXREC 16384             // P2 flat->chunk map capacity (records per tile)

// ---------------------------------------------------------------------------
// Shared binning (bit-identical to the verified round-3..7 semantics):
// XLA canonicalization of (x - X0)/RES -> (x + 20) * 10 in f32, no FMA.
// ---------------------------------------------------------------------------
__device__ __forceinline__ bool bin_point(float x, float y, int& px, int& py) {
    if (!(x >= -20.0f && x < 20.0f && y >= -10.0f && y < 30.0f)) return false;
    float qx = __fmul_rn(__fsub_rn(x, -20.0f), 10.0f);
    float qy = __fmul_rn(__fsub_rn(y, -10.0f), 10.0f);
    px = min(max((int)qx, 0), GW - 1);
    py = min(max((int)qy, 0), GH - 1);
    return true;
}

// Wave-0 exclusive scan of src[0..T_TILES) into dst[0..T_TILES] (dst[T_TILES]=total).
__device__ __forceinline__ void tile_prefix_wave0(const unsigned* src, unsigned* dst) {
    int lane = threadIdx.x;
    if (lane < 64) {
        unsigned run = 0;
        for (int c = 0; c < T_TILES; c += 64) {
            int idx = c + lane;
            unsigned v = (idx < T_TILES) ? src[idx] : 0u;
            unsigned orig = v;
#pragma unroll
            for (int d = 1; d < 64; d <<= 1) {
                unsigned u = __shfl_up(v, d, 64);
                if (lane >= d) v += u;
            }
            if (idx < T_TILES) dst[idx] = run + (v - orig);  // exclusive
            run += __shfl(v, 63, 64);
        }
        if (lane == 0) dst[T_TILES] = run;
    }
}

// Record layout (u64): [key31 : 33] | [i16 : 17] | [local8 : 9] | [tile9 : 0]
//   key31 = f32 bits of max(fadd(z,3),0)  (positive f32 bits < 2^31; monotone;
//           yields EXACT reference h = clip(fmul(fadd(hmax,3),1/7)))
//   i16   = round(inten*256) clamped (8.8 fixed; exact integer summation)
__device__ __forceinline__ bool make_record(float4 p, unsigned long long& rec, int& tile) {
    int px, py;
    if (!bin_point(p.x, p.y, px, py)) return false;
    tile = (py >> 4) * TCOLS + (px >> 4);
    int local = ((py & 15) << 4) | (px & 15);
    unsigned key = __float_as_uint(fmaxf(__fadd_rn(p.z, 3.0f), 0.0f));
    int i16 = min(max((int)rintf(__fmul_rn(p.w, 256.0f)), 0), 65535);
    rec = ((unsigned long long)key << 33) | ((unsigned long long)(unsigned)i16 << 17) |
          ((unsigned long long)(unsigned)local << 9) | (unsigned long long)(unsigned)tile;
    return true;
}

// ---------------------------------------------------------------------------
// P1: fused hist + local-sort + staged scatter. One read of the point cloud.
// Each block owns staging segment [blockIdx*per_block, ...) — records grouped
// by tile via block-local counting sort (LDS buffer). Also zeros ch3/ch4.
// pref_t layout: pref_t[t * B1 + b] = block-local exclusive prefix (t<=T_TILES).
// ---------------------------------------------------------------------------
__global__ __launch_bounds__(256) void p1_kernel(const float4* __restrict__ pts, int n,
                                                 int per_block,
                                                 unsigned long long* __restrict__ staged,
                                                 unsigned* __restrict__ pref_t,
                                                 float* __restrict__ out) {
    __shared__ unsigned long long lbuf[256 * Q];  // transposed [j*256+tid]: conflict-free b64
    __shared__ unsigned cnt[T_TILES];
    __shared__ unsigned pref[T_TILES + 1];
    __shared__ unsigned cur[T_TILES];
    for (int t = threadIdx.x; t < T_TILES; t += 256) cnt[t] = 0;
    // zero ch3/ch4 (polyline stamps run in P2, stream-ordered after P1)
    float4* z4 = (float4*)(out + 3 * GHW);
    for (int j = blockIdx.x * 256 + (int)threadIdx.x; j < (2 * GHW) / 4; j += B1 * 256)
        z4[j] = make_float4(0.0f, 0.0f, 0.0f, 0.0f);
    __syncthreads();

    int start = blockIdx.x * per_block;
    int end = min(start + per_block, n);
    int nmine = 0;
    int i = start + (int)threadIdx.x;
    for (; i + 7 * 256 < end; i += 8 * 256) {
        float4 p[8];
#pragma unroll
        for (int j = 0; j < 8; ++j) p[j] = pts[i + j * 256];
#pragma unroll
        for (int j = 0; j < 8; ++j) {
            unsigned long long r;
            int tile;
            if (make_record(p[j], r, tile)) {
                lbuf[nmine * 256 + threadIdx.x] = r;
                ++nmine;
                atomicAdd(&cnt[tile], 1u);
            }
        }
    }
    for (; i < end; i += 256) {
        unsigned long long r;
        int tile;
        if (make_record(pts[i], r, tile)) {
            lbuf[nmine * 256 + threadIdx.x] = r;
            ++nmine;
            atomicAdd(&cnt[tile], 1u);
        }
    }
    __syncthreads();
    tile_prefix_wave0(cnt, pref);
    __syncthreads();
    for (int t = threadIdx.x; t < T_TILES; t += 256) cur[t] = pref[t];
    for (int t = threadIdx.x; t <= T_TILES; t += 256)
        pref_t[t * B1 + blockIdx.x] = pref[t];
    __syncthreads();
    size_t base = (size_t)blockIdx.x * (size_t)per_block;
    for (int j = 0; j < nmine; ++j) {
        unsigned long long r = lbuf[j * 256 + threadIdx.x];
        int tile = (int)(r & 511u);
        unsigned pos = atomicAdd(&cur[tile], 1u);
        staged[base + pos] = r;  // scattered 8B within 62KB block region; L2 merges
    }
}

// ---------------------------------------------------------------------------
// Polyline segment rasterizer, thread-per-segment (byte-identical math to the
// verified R3..R7 path).
// ---------------------------------------------------------------------------
__device__ void do_poly_segment(int seg, const float2* __restrict__ traj, int ntraj,
                                const float2* __restrict__ osm, int nosm,
                                const float* __restrict__ ego, float* __restrict__ out) {
    int ntseg = ntraj - 1;
    int noseg = nosm - 1;
    if (seg >= ntseg + noseg) return;
    const float2* pts;
    float* out_ch;
    bool use_ego;
    if (seg < ntseg) {
        pts = traj + seg;
        out_ch = out + 3 * GHW;
        use_ego = false;
    } else {
        pts = osm + (seg - ntseg);
        out_ch = out + 4 * GHW;
        use_ego = true;
    }
    float2 P0 = pts[0];
    float2 P1 = pts[1];
    if (use_ego) {
        float yaw = ego[2];
        float cy = cosf(-yaw), sy = sinf(-yaw);
        float ex = ego[0], ey = ego[1];
        float d0x = __fsub_rn(P0.x, ex), d0y = __fsub_rn(P0.y, ey);
        float d1x = __fsub_rn(P1.x, ex), d1y = __fsub_rn(P1.y, ey);
        P0.x = __fsub_rn(__fmul_rn(d0x, cy), __fmul_rn(d0y, sy));
        P0.y = __fadd_rn(__fmul_rn(d0x, sy), __fmul_rn(d0y, cy));
        P1.x = __fsub_rn(__fmul_rn(d1x, cy), __fmul_rn(d1y, sy));
        P1.y = __fadd_rn(__fmul_rn(d1x, sy), __fmul_rn(d1y, cy));
    }
    double ax = trunc(__ddiv_rn(__dadd_rn((double)P0.x, 20.0), 0.1));
    double ay = trunc(__ddiv_rn(__dadd_rn((double)P0.y, 10.0), 0.1));
    double bx = trunc(__ddiv_rn(__dadd_rn((double)P1.x, 20.0), 0.1));
    double by = trunc(__ddiv_rn(__dadd_rn((double)P1.y, 10.0), 0.1));
    bool inA = (ax >= 0.0) && (ax < (double)GW) && (ay >= 0.0) && (ay < (double)GH);
    bool inB = (bx >= 0.0) && (bx < (double)GW) && (by >= 0.0) && (by < (double)GH);
    if (!(inA || inB)) return;
    ax = fmin(fmax(ax, 0.0), (double)(GW - 1));
    ay = fmin(fmax(ay, 0.0), (double)(GH - 1));
    bx = fmin(fmax(bx, 0.0), (double)(GW - 1));
    by = fmin(fmax(by, 0.0), (double)(GH - 1));
    double dx = __dsub_rn(bx, ax);
    double dy = __dsub_rn(by, ay);
    double dmax = fmax(fabs(dx), fabs(dy));
    double denom = fmax(dmax, 1.0);
    int kmax = (int)dmax;
    for (int k = 0; k <= kmax; ++k) {
        double t = __ddiv_rn(fmin((double)k, dmax), denom);
        double ptx = __dadd_rn(ax, __dmul_rn(t, dx));
        double pty = __dadd_rn(ay, __dmul_rn(t, dy));
        int cx = (int)rint(ptx);  // half-to-even
        int cc = (int)rint(pty);
#pragma unroll
        for (int oy = -1; oy <= 1; ++oy) {
#pragma unroll
            for (int ox = -1; ox <= 1; ++ox) {
                int xx = cx + ox;
                int yy = cc + oy;
                if (xx < 0) xx += GW;  // JAX wraps negatives, drops OOB
                if (yy < 0) yy += GH;
                if (xx >= 0 && xx < GW && yy >= 0 && yy < GH) {
                    out_ch[yy * GW + xx] = 1.0f;
                }
            }
        }
    }
}

// Binary-search fallback: find b with fs[b] <= f < fs[b+1].
__device__ __forceinline__ int find_chunk(const unsigned* fs, unsigned f) {
    int lo = 0, hi = B1;
    while (hi - lo > 1) {
        int mid = (lo + hi) >> 1;
        if (fs[mid] <= f) lo = mid;
        else hi = mid;
    }
    return lo;
}

// ---------------------------------------------------------------------------
// P2: blocks [0, T_TILES) gather their tile's records via a FLAT coalesced
// index: wave-scan the 512 run lengths, build flat->chunk u16 map in LDS,
// then consecutive threads read consecutive records (coalesced runs).
// Blocks [T_TILES,...) do polylines.
// ic packs (cnt << 40) | sum_i16 — overflow impossible: 4e6*65280 < 2^40.
// ---------------------------------------------------------------------------
__global__ __launch_bounds__(256) void p2_kernel(const unsigned long long* __restrict__ staged,
                                                 const unsigned* __restrict__ pref_t,
                                                 int per_block, float* __restrict__ out,
                                                 const float2* __restrict__ traj, int ntraj,
                                                 const float2* __restrict__ osm, int nosm,
                                                 const float* __restrict__ ego) {
    if (blockIdx.x >= T_TILES) {
        int seg = (blockIdx.x - T_TILES) * 256 + (int)threadIdx.x;
        do_poly_segment(seg, traj, ntraj, osm, nosm, ego, out);
        return;
    }
    __shared__ unsigned prefA[B1];           // global run start within chunk b
    __shared__ unsigned flatStart[B1 + 1];   // runLen -> exclusive prefix (in place)
    __shared__ unsigned short map16[MAXREC]; // flat index -> chunk b
    __shared__ unsigned zmax[256];           // f32 bits of max(z+3,0); 0 when empty
    __shared__ unsigned long long ic[256];   // (cnt<<40) | sum_i16
    int t = blockIdx.x;
    for (int b = threadIdx.x; b < B1; b += 256) {
        unsigned s = pref_t[t * B1 + b];         // coalesced row reads
        unsigned e = pref_t[(t + 1) * B1 + b];
        prefA[b] = s;
        flatStart[b] = e - s;  // run length (scanned below)
    }
    zmax[threadIdx.x] = 0;
    ic[threadIdx.x] = 0;
    __syncthreads();
    // wave0: exclusive scan over the B1 run lengths, in place
    if (threadIdx.x < 64) {
        int lane = threadIdx.x;
        unsigned run = 0;
        for (int c = 0; c < B1; c += 64) {
            unsigned v = flatStart[c + lane];
            unsigned orig = v;
#pragma unroll
            for (int d = 1; d < 64; d <<= 1) {
                unsigned u = __shfl_up(v, d, 64);
                if (lane >= d) v += u;
            }
            flatStart[c + lane] = run + (v - orig);
            run += __shfl(v, 63, 64);
        }
        if (lane == 0) flatStart[B1] = run;
    }
    __syncthreads();
    unsigned nrec = flatStart[B1];
    bool use_map = (nrec <= MAXREC);
    if (use_map) {
        for (int b = threadIdx.x; b < B1; b += 256) {
            unsigned fs = flatStart[b], fe = flatStart[b + 1];
            for (unsigned k = fs; k < fe; ++k) map16[k] = (unsigned short)b;
        }
    }
    __syncthreads();
    for (unsigned f = threadIdx.x; f < nrec; f += 256) {
        int b = use_map ? (int)map16[f] : find_chunk(flatStart, f);
        unsigned long long r = staged[(size_t)b * (size_t)per_block + prefA[b] +
                                      (f - flatStart[b])];
        int local = (int)((r >> 9) & 255u);
        unsigned key = (unsigned)(r >> 33);
        unsigned long long v16 = (r >> 17) & 0xFFFFull;
        atomicMax(&zmax[local], key);
        atomicAdd(&ic[local], (1ull << 40) | v16);
    }
    __syncthreads();
    int l = threadIdx.x;
    int trow = t / TCOLS, tcol = t % TCOLS;
    int gy = trow * 16 + (l >> 4);
    int gx = tcol * 16 + (l & 15);
    if (gy < GH) {
        const float inv7 = 1.0f / 7.0f;
        const float invlog129 = 1.0f / 4.8598124043616719e+00f;  // 1/log(129)
        unsigned long long v = ic[l];
        float h, ich, dd;
        if (v == 0) {
            h = fminf(fmaxf(__fmul_rn(3.0f, inv7), 0.0f), 1.0f);  // empty: clip(3/7)
            ich = 0.0f;
            dd = 0.0f;
        } else {
            unsigned cnt = (unsigned)(v >> 40);
            float sum16 = (float)(v & ((1ull << 40) - 1));        // exact (< 2^24)
            float keyf = __uint_as_float(zmax[l]);                // = max(fadd(hmax,3),0)
            h = fminf(fmaxf(__fmul_rn(keyf, inv7), 0.0f), 1.0f);  // exact reference h
            ich = fminf(__fdiv_rn(sum16, __fmul_rn((float)cnt, 65280.0f)), 1.0f);
            dd = fminf(__fmul_rn(log1pf((float)cnt), invlog129), 1.0f);
        }
        int idx = gy * GW + gx;
        out[0 * GHW + idx] = h;
        out[1 * GHW + idx] = ich;
        out[2 * GHW + idx] = dd;
    }
}

// Standalone polyline kernel (fallback path).
__global__ __launch_bounds__(256) void polylines_kernel(const float2* __restrict__ traj,
                                                        int ntraj,
                                                        const float2* __restrict__ osm, int nosm,
                                                        const float* __restrict__ ego,
                                                        float* __restrict__ out) {
    int seg = blockIdx.x * 256 + (int)threadIdx.x;
    do_poly_segment(seg, traj, ntraj, osm, nosm, ego, out);
}

// ======================== fallback (round-3) path ==========================
__global__ __launch_bounds__(256) void init_kernel(float* __restrict__ out) {
    int i = blockIdx.x * blockDim.x + threadIdx.x;
    if (i < GHW) {
        out[0 * GHW + i] = -INFINITY;
        out[1 * GHW + i] = 0.0f;
        out[2 * GHW + i] = 0.0f;
        out[3 * GHW + i] = 0.0f;
        out[4 * GHW + i] = 0.0f;
    }
}

__device__ __forceinline__ void atomicMaxFloat(float* addr, float val) {
    if (val >= 0.0f) {
        atomicMax((int*)addr, __float_as_int(val));
    } else {
        atomicMin((unsigned int*)addr, (unsigned int)__float_as_int(val));
    }
}

__global__ __launch_bounds__(256) void lidar_kernel(const float4* __restrict__ pts, int n,
                                                    float* __restrict__ out) {
    int i = blockIdx.x * blockDim.x + threadIdx.x;
    if (i >= n) return;
    float4 p = pts[i];
    int px, py;
    if (!bin_point(p.x, p.y, px, py)) return;
    int idx = py * GW + px;
    atomicMaxFloat(&out[0 * GHW + idx], p.z);
    atomicAdd(&out[1 * GHW + idx], p.w);
    atomicAdd(&out[2 * GHW + idx], 1.0f);
}

__global__ __launch_bounds__(256) void finalize_kernel(float* __restrict__ out) {
    int i = blockIdx.x * blockDim.x + threadIdx.x;
    if (i >= GHW) return;
    float hm = out[0 * GHW + i];
    float isum = out[1 * GHW + i];
    float c = out[2 * GHW + i];
    if (hm == -INFINITY) hm = 0.0f;
    const float inv7 = 1.0f / 7.0f;
    const float inv255 = 1.0f / 255.0f;
    const float invlog129 = 1.0f / 4.8598124043616719e+00f;
    float h = fminf(fmaxf(__fmul_rn(__fadd_rn(hm, 3.0f), inv7), 0.0f), 1.0f);
    float im = (c > 0.0f) ? __fdiv_rn(isum, fmaxf(c, 1.0f)) : 0.0f;
    float ich = fminf(fmaxf(__fmul_rn(im, inv255), 0.0f), 1.0f);
    float dd = fminf(fmaxf(__fmul_rn(log1pf(c), invlog129), 0.0f), 1.0f);
    out[0 * GHW + i] = h;
    out[1 * GHW + i] = ich;
    out[2 * GHW + i] = dd;
}

extern "C" void kernel_launch(void* const* d_in, const int* in_sizes, int n_in,
                              void* d_out, int out_size, void* d_ws, size_t ws_size,
                              hipStream_t stream) {
    const float* lidar = (const float*)d_in[0];
    const float* traj = (const float*)d_in[1];
    const float* osm = (const float*)d_in[2];
    const float* ego = (const float*)d_in[3];
    float* out = (float*)d_out;

    int n_lidar = in_sizes[0] / 4;
    int n_traj = in_sizes[1] / 2;
    int n_osm = in_sizes[2] / 2;
    int nseg = (n_traj - 1) + (n_osm - 1);
    int npb = (nseg + 255) / 256;

    int per_block = (n_lidar + B1 - 1) / B1;
    size_t staged_bytes = (size_t)B1 * (size_t)per_block * 8;
    size_t pref_bytes = (size_t)(T_TILES + 1) * B1 * 4;
    size_t need = staged_bytes + pref_bytes;

    if (ws_size >= need && per_block <= 256 * Q) {
        char* w = (char*)d_ws;
        unsigned long long* staged = (unsigned long long*)w;
        unsigned* pref_t = (unsigned*)(w + staged_bytes);

        p1_kernel<<<B1, 256, 0, stream>>>((const float4*)lidar, n_lidar, per_block, staged,
                                          pref_t, out);
        p2_kernel<<<T_TILES + npb, 256, 0, stream>>>(staged, pref_t, per_block, out,
                                                     (const float2*)traj, n_traj,
                                                     (const float2*)osm, n_osm, ego);
    } else {
        // fallback: verified round-3 atomic path
        init_kernel<<<(GHW + 255) / 256, 256, 0, stream>>>(out);
        lidar_kernel<<<(n_lidar + 255) / 256, 256, 0, stream>>>((const float4*)lidar, n_lidar,
                                                                out);
        finalize_kernel<<<(GHW + 255) / 256, 256, 0, stream>>>(out);
        polylines_kernel<<<(nseg + 255) / 256, 256, 0, stream>>>((const float2*)traj, n_traj,
                                                                 (const float2*)osm, n_osm, ego,
                                                                 out);
    }
}

// Round 9
// 157.519 us; speedup vs baseline: 1.4397x; 1.4397x over previous
//
#include <hip/hip_runtime.h>
#include <math.h>

#define GH 300
#define GW 400
#define GHW (GH * GW)

// Tile grid: 16x16 cells per tile
#define TCOLS 25                 // 400/16
#define TROWS 19                 // ceil(300/16)
#define T_TILES (TCOLS * TROWS)  // 475
#define B1 512                   // P1 blocks
#define Q 32                     // per-thread LDS record quota (per_block <= 8192)
#define S2 4                     // P2a sub-blocks per tile (each owns 128 chunks)

// ---------------------------------------------------------------------------
// Shared binning (bit-identical to the verified round-3..8 semantics):
// XLA canonicalization of (x - X0)/RES -> (x + 20) * 10 in f32, no FMA.
// ---------------------------------------------------------------------------
__device__ __forceinline__ bool bin_point(float x, float y, int& px, int& py) {
    if (!(x >= -20.0f && x < 20.0f && y >= -10.0f && y < 30.0f)) return false;
    float qx = __fmul_rn(__fsub_rn(x, -20.0f), 10.0f);
    float qy = __fmul_rn(__fsub_rn(y, -10.0f), 10.0f);
    px = min(max((int)qx, 0), GW - 1);
    py = min(max((int)qy, 0), GH - 1);
    return true;
}

// Wave-0 exclusive scan of src[0..T_TILES) into dst[0..T_TILES] (dst[T_TILES]=total).
__device__ __forceinline__ void tile_prefix_wave0(const unsigned* src, unsigned* dst) {
    int lane = threadIdx.x;
    if (lane < 64) {
        unsigned run = 0;
        for (int c = 0; c < T_TILES; c += 64) {
            int idx = c + lane;
            unsigned v = (idx < T_TILES) ? src[idx] : 0u;
            unsigned orig = v;
#pragma unroll
            for (int d = 1; d < 64; d <<= 1) {
                unsigned u = __shfl_up(v, d, 64);
                if (lane >= d) v += u;
            }
            if (idx < T_TILES) dst[idx] = run + (v - orig);  // exclusive
            run += __shfl(v, 63, 64);
        }
        if (lane == 0) dst[T_TILES] = run;
    }
}

// Record layout (u64): [key31 : 33] | [i16 : 17] | [local8 : 9] | [tile9 : 0]
//   key31 = f32 bits of max(fadd(z,3),0)  (positive f32 bits < 2^31; monotone;
//           yields EXACT reference h = clip(fmul(fadd(hmax,3),1/7)))
//   i16   = round(inten*256) clamped (8.8 fixed; exact integer summation)
__device__ __forceinline__ bool make_record(float4 p, unsigned long long& rec, int& tile) {
    int px, py;
    if (!bin_point(p.x, p.y, px, py)) return false;
    tile = (py >> 4) * TCOLS + (px >> 4);
    int local = ((py & 15) << 4) | (px & 15);
    unsigned key = __float_as_uint(fmaxf(__fadd_rn(p.z, 3.0f), 0.0f));
    int i16 = min(max((int)rintf(__fmul_rn(p.w, 256.0f)), 0), 65535);
    rec = ((unsigned long long)key << 33) | ((unsigned long long)(unsigned)i16 << 17) |
          ((unsigned long long)(unsigned)local << 9) | (unsigned long long)(unsigned)tile;
    return true;
}

// ---------------------------------------------------------------------------
// P1: fused hist + local-sort + staged scatter. One read of the point cloud.
// Each block owns staging segment [blockIdx*per_block, ...) — records grouped
// by tile via block-local counting sort (LDS buffer). Also zeros ch3/ch4.
// pref_t layout: pref_t[t * B1 + b] = block-local exclusive prefix (t<=T_TILES).
// ---------------------------------------------------------------------------
__global__ __launch_bounds__(256) void p1_kernel(const float4* __restrict__ pts, int n,
                                                 int per_block,
                                                 unsigned long long* __restrict__ staged,
                                                 unsigned* __restrict__ pref_t,
                                                 float* __restrict__ out) {
    __shared__ unsigned long long lbuf[256 * Q];  // transposed [j*256+tid]: conflict-free b64
    __shared__ unsigned cnt[T_TILES];
    __shared__ unsigned pref[T_TILES + 1];
    __shared__ unsigned cur[T_TILES];
    for (int t = threadIdx.x; t < T_TILES; t += 256) cnt[t] = 0;
    // zero ch3/ch4 (polyline stamps run in P2b, stream-ordered after P1)
    float4* z4 = (float4*)(out + 3 * GHW);
    for (int j = blockIdx.x * 256 + (int)threadIdx.x; j < (2 * GHW) / 4; j += B1 * 256)
        z4[j] = make_float4(0.0f, 0.0f, 0.0f, 0.0f);
    __syncthreads();

    int start = blockIdx.x * per_block;
    int end = min(start + per_block, n);
    int nmine = 0;
    int i = start + (int)threadIdx.x;
    for (; i + 7 * 256 < end; i += 8 * 256) {
        float4 p[8];
#pragma unroll
        for (int j = 0; j < 8; ++j) p[j] = pts[i + j * 256];
#pragma unroll
        for (int j = 0; j < 8; ++j) {
            unsigned long long r;
            int tile;
            if (make_record(p[j], r, tile)) {
                lbuf[nmine * 256 + threadIdx.x] = r;
                ++nmine;
                atomicAdd(&cnt[tile], 1u);
            }
        }
    }
    for (; i < end; i += 256) {
        unsigned long long r;
        int tile;
        if (make_record(pts[i], r, tile)) {
            lbuf[nmine * 256 + threadIdx.x] = r;
            ++nmine;
            atomicAdd(&cnt[tile], 1u);
        }
    }
    __syncthreads();
    tile_prefix_wave0(cnt, pref);
    __syncthreads();
    for (int t = threadIdx.x; t < T_TILES; t += 256) cur[t] = pref[t];
    for (int t = threadIdx.x; t <= T_TILES; t += 256)
        pref_t[t * B1 + blockIdx.x] = pref[t];
    __syncthreads();
    size_t base = (size_t)blockIdx.x * (size_t)per_block;
    for (int j = 0; j < nmine; ++j) {
        unsigned long long r = lbuf[j * 256 + threadIdx.x];
        int tile = (int)(r & 511u);
        unsigned pos = atomicAdd(&cur[tile], 1u);
        staged[base + pos] = r;  // scattered 8B within 62KB block region; L2 merges
    }
}

// ---------------------------------------------------------------------------
// P2a: sub-tile accumulation. Grid = T_TILES * S2, blockDim = 128.
// Block (t, s): thread tid owns chunk b = s*128 + tid (exactly one chunk),
// walks its ~10-record run, LDS-accumulates, writes 256-cell partials
// non-atomically (coalesced). 1900 blocks -> real occupancy, latency hidden.
// ---------------------------------------------------------------------------
__global__ __launch_bounds__(128) void p2a_kernel(const unsigned long long* __restrict__ staged,
                                                  const unsigned* __restrict__ pref_t,
                                                  int per_block,
                                                  unsigned* __restrict__ part_z,
                                                  unsigned long long* __restrict__ part_ic) {
    __shared__ unsigned zmax[256];          // f32 bits of max(z+3,0); 0 when empty
    __shared__ unsigned long long ic[256];  // (cnt<<40) | sum_i16
    int t = blockIdx.x / S2;
    int s = blockIdx.x % S2;
    for (int l = threadIdx.x; l < 256; l += 128) {
        zmax[l] = 0;
        ic[l] = 0;
    }
    __syncthreads();
    int b = s * 128 + (int)threadIdx.x;  // one chunk per thread (B1 = S2*128)
    unsigned ks = pref_t[t * B1 + b];          // coalesced
    unsigned ke = pref_t[(t + 1) * B1 + b];
    size_t base = (size_t)b * (size_t)per_block;
    for (unsigned k = ks; k < ke; ++k) {
        unsigned long long r = staged[base + k];
        int local = (int)((r >> 9) & 255u);
        unsigned key = (unsigned)(r >> 33);
        unsigned long long v16 = (r >> 17) & 0xFFFFull;
        atomicMax(&zmax[local], key);
        atomicAdd(&ic[local], (1ull << 40) | v16);
    }
    __syncthreads();
    size_t pbase = (size_t)(t * S2 + s) * 256;
    for (int l = threadIdx.x; l < 256; l += 128) {
        part_z[pbase + l] = zmax[l];
        part_ic[pbase + l] = ic[l];
    }
}

// ---------------------------------------------------------------------------
// Polyline segment rasterizer, thread-per-segment (byte-identical math to the
// verified R3..R8 path).
// ---------------------------------------------------------------------------
__device__ void do_poly_segment(int seg, const float2* __restrict__ traj, int ntraj,
                                const float2* __restrict__ osm, int nosm,
                                const float* __restrict__ ego, float* __restrict__ out) {
    int ntseg = ntraj - 1;
    int noseg = nosm - 1;
    if (seg >= ntseg + noseg) return;
    const float2* pts;
    float* out_ch;
    bool use_ego;
    if (seg < ntseg) {
        pts = traj + seg;
        out_ch = out + 3 * GHW;
        use_ego = false;
    } else {
        pts = osm + (seg - ntseg);
        out_ch = out + 4 * GHW;
        use_ego = true;
    }
    float2 P0 = pts[0];
    float2 P1 = pts[1];
    if (use_ego) {
        float yaw = ego[2];
        float cy = cosf(-yaw), sy = sinf(-yaw);
        float ex = ego[0], ey = ego[1];
        float d0x = __fsub_rn(P0.x, ex), d0y = __fsub_rn(P0.y, ey);
        float d1x = __fsub_rn(P1.x, ex), d1y = __fsub_rn(P1.y, ey);
        P0.x = __fsub_rn(__fmul_rn(d0x, cy), __fmul_rn(d0y, sy));
        P0.y = __fadd_rn(__fmul_rn(d0x, sy), __fmul_rn(d0y, cy));
        P1.x = __fsub_rn(__fmul_rn(d1x, cy), __fmul_rn(d1y, sy));
        P1.y = __fadd_rn(__fmul_rn(d1x, sy), __fmul_rn(d1y, cy));
    }
    double ax = trunc(__ddiv_rn(__dadd_rn((double)P0.x, 20.0), 0.1));
    double ay = trunc(__ddiv_rn(__dadd_rn((double)P0.y, 10.0), 0.1));
    double bx = trunc(__ddiv_rn(__dadd_rn((double)P1.x, 20.0), 0.1));
    double by = trunc(__ddiv_rn(__dadd_rn((double)P1.y, 10.0), 0.1));
    bool inA = (ax >= 0.0) && (ax < (double)GW) && (ay >= 0.0) && (ay < (double)GH);
    bool inB = (bx >= 0.0) && (bx < (double)GW) && (by >= 0.0) && (by < (double)GH);
    if (!(inA || inB)) return;
    ax = fmin(fmax(ax, 0.0), (double)(GW - 1));
    ay = fmin(fmax(ay, 0.0), (double)(GH - 1));
    bx = fmin(fmax(bx, 0.0), (double)(GW - 1));
    by = fmin(fmax(by, 0.0), (double)(GH - 1));
    double dx = __dsub_rn(bx, ax);
    double dy = __dsub_rn(by, ay);
    double dmax = fmax(fabs(dx), fabs(dy));
    double denom = fmax(dmax, 1.0);
    int kmax = (int)dmax;
    for (int k = 0; k <= kmax; ++k) {
        double t = __ddiv_rn(fmin((double)k, dmax), denom);
        double ptx = __dadd_rn(ax, __dmul_rn(t, dx));
        double pty = __dadd_rn(ay, __dmul_rn(t, dy));
        int cx = (int)rint(ptx);  // half-to-even
        int cc = (int)rint(pty);
#pragma unroll
        for (int oy = -1; oy <= 1; ++oy) {
#pragma unroll
            for (int ox = -1; ox <= 1; ++ox) {
                int xx = cx + ox;
                int yy = cc + oy;
                if (xx < 0) xx += GW;  // JAX wraps negatives, drops OOB
                if (yy < 0) yy += GH;
                if (xx >= 0 && xx < GW && yy >= 0 && yy < GH) {
                    out_ch[yy * GW + xx] = 1.0f;
                }
            }
        }
    }
}

// ---------------------------------------------------------------------------
// P2b: blocks [0, T_TILES) reduce the S2 partials per cell (coalesced) and
// finalize; blocks [T_TILES,...) do polylines.
// ---------------------------------------------------------------------------
__global__ __launch_bounds__(256) void p2b_kernel(const unsigned* __restrict__ part_z,
                                                  const unsigned long long* __restrict__ part_ic,
                                                  float* __restrict__ out,
                                                  const float2* __restrict__ traj, int ntraj,
                                                  const float2* __restrict__ osm, int nosm,
                                                  const float* __restrict__ ego) {
    if (blockIdx.x >= T_TILES) {
        int seg = (blockIdx.x - T_TILES) * 256 + (int)threadIdx.x;
        do_poly_segment(seg, traj, ntraj, osm, nosm, ego, out);
        return;
    }
    int t = blockIdx.x;
    int l = threadIdx.x;
    size_t pbase = (size_t)t * S2 * 256;
    unsigned zfin = 0;
    unsigned long long v = 0;
#pragma unroll
    for (int s = 0; s < S2; ++s) {
        zfin = max(zfin, part_z[pbase + s * 256 + l]);  // coalesced across l
        v += part_ic[pbase + s * 256 + l];              // cnt<<40 | sum merge-adds
    }
    int trow = t / TCOLS, tcol = t % TCOLS;
    int gy = trow * 16 + (l >> 4);
    int gx = tcol * 16 + (l & 15);
    if (gy < GH) {
        const float inv7 = 1.0f / 7.0f;
        const float invlog129 = 1.0f / 4.8598124043616719e+00f;  // 1/log(129)
        float h, ich, dd;
        if (v == 0) {
            h = fminf(fmaxf(__fmul_rn(3.0f, inv7), 0.0f), 1.0f);  // empty: clip(3/7)
            ich = 0.0f;
            dd = 0.0f;
        } else {
            unsigned cnt = (unsigned)(v >> 40);
            float sum16 = (float)(v & ((1ull << 40) - 1));        // exact (< 2^24)
            float keyf = __uint_as_float(zfin);                   // = max(fadd(hmax,3),0)
            h = fminf(fmaxf(__fmul_rn(keyf, inv7), 0.0f), 1.0f);  // exact reference h
            ich = fminf(__fdiv_rn(sum16, __fmul_rn((float)cnt, 65280.0f)), 1.0f);
            dd = fminf(__fmul_rn(log1pf((float)cnt), invlog129), 1.0f);
        }
        int idx = gy * GW + gx;
        out[0 * GHW + idx] = h;
        out[1 * GHW + idx] = ich;
        out[2 * GHW + idx] = dd;
    }
}

// Standalone polyline kernel (fallback path).
__global__ __launch_bounds__(256) void polylines_kernel(const float2* __restrict__ traj,
                                                        int ntraj,
                                                        const float2* __restrict__ osm, int nosm,
                                                        const float* __restrict__ ego,
                                                        float* __restrict__ out) {
    int seg = blockIdx.x * 256 + (int)threadIdx.x;
    do_poly_segment(seg, traj, ntraj, osm, nosm, ego, out);
}

// ======================== fallback (round-3) path ==========================
__global__ __launch_bounds__(256) void init_kernel(float* __restrict__ out) {
    int i = blockIdx.x * blockDim.x + threadIdx.x;
    if (i < GHW) {
        out[0 * GHW + i] = -INFINITY;
        out[1 * GHW + i] = 0.0f;
        out[2 * GHW + i] = 0.0f;
        out[3 * GHW + i] = 0.0f;
        out[4 * GHW + i] = 0.0f;
    }
}

__device__ __forceinline__ void atomicMaxFloat(float* addr, float val) {
    if (val >= 0.0f) {
        atomicMax((int*)addr, __float_as_int(val));
    } else {
        atomicMin((unsigned int*)addr, (unsigned int)__float_as_int(val));
    }
}

__global__ __launch_bounds__(256) void lidar_kernel(const float4* __restrict__ pts, int n,
                                                    float* __restrict__ out) {
    int i = blockIdx.x * blockDim.x + threadIdx.x;
    if (i >= n) return;
    float4 p = pts[i];
    int px, py;
    if (!bin_point(p.x, p.y, px, py)) return;
    int idx = py * GW + px;
    atomicMaxFloat(&out[0 * GHW + idx], p.z);
    atomicAdd(&out[1 * GHW + idx], p.w);
    atomicAdd(&out[2 * GHW + idx], 1.0f);
}

__global__ __launch_bounds__(256) void finalize_kernel(float* __restrict__ out) {
    int i = blockIdx.x * blockDim.x + threadIdx.x;
    if (i >= GHW) return;
    float hm = out[0 * GHW + i];
    float isum = out[1 * GHW + i];
    float c = out[2 * GHW + i];
    if (hm == -INFINITY) hm = 0.0f;
    const float inv7 = 1.0f / 7.0f;
    const float inv255 = 1.0f / 255.0f;
    const float invlog129 = 1.0f / 4.8598124043616719e+00f;
    float h = fminf(fmaxf(__fmul_rn(__fadd_rn(hm, 3.0f), inv7), 0.0f), 1.0f);
    float im = (c > 0.0f) ? __fdiv_rn(isum, fmaxf(c, 1.0f)) : 0.0f;
    float ich = fminf(fmaxf(__fmul_rn(im, inv255), 0.0f), 1.0f);
    float dd = fminf(fmaxf(__fmul_rn(log1pf(c), invlog129), 0.0f), 1.0f);
    out[0 * GHW + i] = h;
    out[1 * GHW + i] = ich;
    out[2 * GHW + i] = dd;
}

extern "C" void kernel_launch(void* const* d_in, const int* in_sizes, int n_in,
                              void* d_out, int out_size, void* d_ws, size_t ws_size,
                              hipStream_t stream) {
    const float* lidar = (const float*)d_in[0];
    const float* traj = (const float*)d_in[1];
    const float* osm = (const float*)d_in[2];
    const float* ego = (const float*)d_in[3];
    float* out = (float*)d_out;

    int n_lidar = in_sizes[0] / 4;
    int n_traj = in_sizes[1] / 2;
    int n_osm = in_sizes[2] / 2;
    int nseg = (n_traj - 1) + (n_osm - 1);
    int npb = (nseg + 255) / 256;

    int per_block = (n_lidar + B1 - 1) / B1;
    size_t staged_bytes = (size_t)B1 * (size_t)per_block * 8;
    size_t pic_bytes = (size_t)T_TILES * S2 * 256 * 8;
    size_t pz_bytes = (size_t)T_TILES * S2 * 256 * 4;
    size_t pref_bytes = (size_t)(T_TILES + 1) * B1 * 4;
    size_t need = staged_bytes + pic_bytes + pz_bytes + pref_bytes;

    if (ws_size >= need && per_block <= 256 * Q) {
        char* w = (char*)d_ws;
        unsigned long long* staged = (unsigned long long*)w;
        unsigned long long* part_ic = (unsigned long long*)(w + staged_bytes);
        unsigned* part_z = (unsigned*)(w + staged_bytes + pic_bytes);
        unsigned* pref_t = (unsigned*)(w + staged_bytes + pic_bytes + pz_bytes);

        p1_kernel<<<B1, 256, 0, stream>>>((const float4*)lidar, n_lidar, per_block, staged,
                                          pref_t, out);
        p2a_kernel<<<T_TILES * S2, 128, 0, stream>>>(staged, pref_t, per_block, part_z, part_ic);
        p2b_kernel<<<T_TILES + npb, 256, 0, stream>>>(part_z, part_ic, out,
                                                      (const float2*)traj, n_traj,
                                                      (const float2*)osm, n_osm, ego);
    } else {
        // fallback: verified round-3 atomic path
        init_kernel<<<(GHW + 255) / 256, 256, 0, stream>>>(out);
        lidar_kernel<<<(n_lidar + 255) / 256, 256, 0, stream>>>((const float4*)lidar, n_lidar,
                                                                out);
        finalize_kernel<<<(GHW + 255) / 256, 256, 0, stream>>>(out);
        polylines_kernel<<<(nseg + 255) / 256, 256, 0, stream>>>((const float2*)traj, n_traj,
                                                                 (const float2*)osm, n_osm, ego,
                                                                 out);
    }
}

// Round 10
// 146.406 us; speedup vs baseline: 1.5490x; 1.0759x over previous
//
#include <hip/hip_runtime.h>
#include <math.h>

#define GH 300
#define GW 400
#define GHW (GH * GW)

// Tile grid: 16x16 cells per tile
#define TCOLS 25                 // 400/16
#define TROWS 19                 // ceil(300/16)
#define T_TILES (TCOLS * TROWS)  // 475
#define B1 1024                  // P1 blocks / staging chunks
#define Q 16                     // per-thread LDS record quota (per_block <= 4096)
#define S2 4                     // P2a sub-blocks per tile (4 x 256 threads = 1024 chunks)

// ---------------------------------------------------------------------------
// Shared binning (bit-identical to the verified round-3..9 semantics):
// XLA canonicalization of (x - X0)/RES -> (x + 20) * 10 in f32, no FMA.
// ---------------------------------------------------------------------------
__device__ __forceinline__ bool bin_point(float x, float y, int& px, int& py) {
    if (!(x >= -20.0f && x < 20.0f && y >= -10.0f && y < 30.0f)) return false;
    float qx = __fmul_rn(__fsub_rn(x, -20.0f), 10.0f);
    float qy = __fmul_rn(__fsub_rn(y, -10.0f), 10.0f);
    px = min(max((int)qx, 0), GW - 1);
    py = min(max((int)qy, 0), GH - 1);
    return true;
}

// Wave-0 exclusive scan of src[0..T_TILES) into dst[0..T_TILES] (dst[T_TILES]=total).
__device__ __forceinline__ void tile_prefix_wave0(const unsigned* src, unsigned* dst) {
    int lane = threadIdx.x;
    if (lane < 64) {
        unsigned run = 0;
        for (int c = 0; c < T_TILES; c += 64) {
            int idx = c + lane;
            unsigned v = (idx < T_TILES) ? src[idx] : 0u;
            unsigned orig = v;
#pragma unroll
            for (int d = 1; d < 64; d <<= 1) {
                unsigned u = __shfl_up(v, d, 64);
                if (lane >= d) v += u;
            }
            if (idx < T_TILES) dst[idx] = run + (v - orig);  // exclusive
            run += __shfl(v, 63, 64);
        }
        if (lane == 0) dst[T_TILES] = run;
    }
}

// Record (u32): [z16 : 16] | [i8 : 8] | [local8 : 0]   (tile implicit via pref_t)
//   z16 = round((z+3)*65535/7) clamped — h quantization err 7.6e-6 (R4/5-verified)
//   i8  = round(inten) clamped [0,255] — adds <= 0.5/255 ~ 2e-3 to ich (tol 2e-2)
__device__ __forceinline__ bool make_record(float4 p, unsigned& rec, int& tile) {
    int px, py;
    if (!bin_point(p.x, p.y, px, py)) return false;
    tile = (py >> 4) * TCOLS + (px >> 4);
    int local = ((py & 15) << 4) | (px & 15);
    int z16 = min(max((int)rintf(__fmul_rn(__fadd_rn(p.z, 3.0f), 65535.0f / 7.0f)), 0), 65535);
    int i8 = min(max((int)rintf(p.w), 0), 255);
    rec = ((unsigned)z16 << 16) | ((unsigned)i8 << 8) | (unsigned)local;
    return true;
}

// ---------------------------------------------------------------------------
// P1: fused hist + local-sort + staged scatter. One read of the point cloud.
// Block b owns staging chunk [b*per_block ...): records grouped by tile via
// block-local counting sort (u32 LDS buf + u16 tile buf: ~30 KB -> 5 blk/CU).
// Also zeros ch3/ch4. pref_t[t * B1 + b] = block-local exclusive prefix.
// ---------------------------------------------------------------------------
__global__ __launch_bounds__(256) void p1_kernel(const float4* __restrict__ pts, int n,
                                                 int per_block,
                                                 unsigned* __restrict__ staged,
                                                 unsigned* __restrict__ pref_t,
                                                 float* __restrict__ out) {
    __shared__ unsigned lbuf[256 * Q];        // transposed [j*256+tid]
    __shared__ unsigned short ltile[256 * Q];
    __shared__ unsigned cnt[T_TILES];
    __shared__ unsigned pref[T_TILES + 1];
    __shared__ unsigned cur[T_TILES];
    for (int t = threadIdx.x; t < T_TILES; t += 256) cnt[t] = 0;
    // zero ch3/ch4 (polyline stamps run in P2b, stream-ordered after P1)
    float4* z4 = (float4*)(out + 3 * GHW);
    for (int j = blockIdx.x * 256 + (int)threadIdx.x; j < (2 * GHW) / 4; j += B1 * 256)
        z4[j] = make_float4(0.0f, 0.0f, 0.0f, 0.0f);
    __syncthreads();

    int start = blockIdx.x * per_block;
    int end = min(start + per_block, n);
    int nmine = 0;
    int i = start + (int)threadIdx.x;
    for (; i + 7 * 256 < end; i += 8 * 256) {
        float4 p[8];
#pragma unroll
        for (int j = 0; j < 8; ++j) p[j] = pts[i + j * 256];
#pragma unroll
        for (int j = 0; j < 8; ++j) {
            unsigned r;
            int tile;
            if (make_record(p[j], r, tile)) {
                lbuf[nmine * 256 + threadIdx.x] = r;
                ltile[nmine * 256 + threadIdx.x] = (unsigned short)tile;
                ++nmine;
                atomicAdd(&cnt[tile], 1u);
            }
        }
    }
    for (; i < end; i += 256) {
        unsigned r;
        int tile;
        if (make_record(pts[i], r, tile)) {
            lbuf[nmine * 256 + threadIdx.x] = r;
            ltile[nmine * 256 + threadIdx.x] = (unsigned short)tile;
            ++nmine;
            atomicAdd(&cnt[tile], 1u);
        }
    }
    __syncthreads();
    tile_prefix_wave0(cnt, pref);
    __syncthreads();
    for (int t = threadIdx.x; t < T_TILES; t += 256) cur[t] = pref[t];
    for (int t = threadIdx.x; t <= T_TILES; t += 256)
        pref_t[t * B1 + blockIdx.x] = pref[t];
    __syncthreads();
    size_t base = (size_t)blockIdx.x * (size_t)per_block;
    for (int j = 0; j < nmine; ++j) {
        unsigned r = lbuf[j * 256 + threadIdx.x];
        int tile = (int)ltile[j * 256 + threadIdx.x];
        unsigned pos = atomicAdd(&cur[tile], 1u);
        staged[base + pos] = r;  // scattered 4B within ~15.6KB block region; L2 merges
    }
}

// ---------------------------------------------------------------------------
// P2a: sub-tile accumulation. Grid = T_TILES * S2, blockDim = 256.
// Block (t, s): thread tid owns chunk b = s*256 + tid (exactly one of B1=1024),
// walks its ~4-record run, LDS-accumulates, writes 256-cell partials
// non-atomically (coalesced).
// ic packs (cnt << 32) | sum_i8 — cnt <= 2^22, sum_i8 <= 2^30: no overflow,
// and S2-way partial merge by addition stays carry-safe.
// ---------------------------------------------------------------------------
__global__ __launch_bounds__(256) void p2a_kernel(const unsigned* __restrict__ staged,
                                                  const unsigned* __restrict__ pref_t,
                                                  int per_block,
                                                  unsigned* __restrict__ part_z,
                                                  unsigned long long* __restrict__ part_ic) {
    __shared__ unsigned zmax[256];          // z16 max (0 when empty is safe: z16>=0)
    __shared__ unsigned long long ic[256];  // (cnt<<32) | sum_i8
    int t = blockIdx.x / S2;
    int s = blockIdx.x % S2;
    zmax[threadIdx.x] = 0;
    ic[threadIdx.x] = 0;
    __syncthreads();
    int b = s * 256 + (int)threadIdx.x;  // one chunk per thread (B1 = S2*256)
    unsigned ks = pref_t[t * B1 + b];    // coalesced
    unsigned ke = pref_t[(t + 1) * B1 + b];
    size_t base = (size_t)b * (size_t)per_block;
    for (unsigned k = ks; k < ke; ++k) {
        unsigned r = staged[base + k];
        int local = (int)(r & 255u);
        unsigned z16 = r >> 16;
        unsigned long long i8 = (r >> 8) & 255ull;
        atomicMax(&zmax[local], z16);
        atomicAdd(&ic[local], (1ull << 32) | i8);
    }
    __syncthreads();
    size_t pbase = (size_t)(t * S2 + s) * 256;
    part_z[pbase + threadIdx.x] = zmax[threadIdx.x];
    part_ic[pbase + threadIdx.x] = ic[threadIdx.x];
}

// ---------------------------------------------------------------------------
// Polyline segment rasterizer, thread-per-segment (byte-identical math to the
// verified R3..R9 path).
// ---------------------------------------------------------------------------
__device__ void do_poly_segment(int seg, const float2* __restrict__ traj, int ntraj,
                                const float2* __restrict__ osm, int nosm,
                                const float* __restrict__ ego, float* __restrict__ out) {
    int ntseg = ntraj - 1;
    int noseg = nosm - 1;
    if (seg >= ntseg + noseg) return;
    const float2* pts;
    float* out_ch;
    bool use_ego;
    if (seg < ntseg) {
        pts = traj + seg;
        out_ch = out + 3 * GHW;
        use_ego = false;
    } else {
        pts = osm + (seg - ntseg);
        out_ch = out + 4 * GHW;
        use_ego = true;
    }
    float2 P0 = pts[0];
    float2 P1 = pts[1];
    if (use_ego) {
        float yaw = ego[2];
        float cy = cosf(-yaw), sy = sinf(-yaw);
        float ex = ego[0], ey = ego[1];
        float d0x = __fsub_rn(P0.x, ex), d0y = __fsub_rn(P0.y, ey);
        float d1x = __fsub_rn(P1.x, ex), d1y = __fsub_rn(P1.y, ey);
        P0.x = __fsub_rn(__fmul_rn(d0x, cy), __fmul_rn(d0y, sy));
        P0.y = __fadd_rn(__fmul_rn(d0x, sy), __fmul_rn(d0y, cy));
        P1.x = __fsub_rn(__fmul_rn(d1x, cy), __fmul_rn(d1y, sy));
        P1.y = __fadd_rn(__fmul_rn(d1x, sy), __fmul_rn(d1y, cy));
    }
    double ax = trunc(__ddiv_rn(__dadd_rn((double)P0.x, 20.0), 0.1));
    double ay = trunc(__ddiv_rn(__dadd_rn((double)P0.y, 10.0), 0.1));
    double bx = trunc(__ddiv_rn(__dadd_rn((double)P1.x, 20.0), 0.1));
    double by = trunc(__ddiv_rn(__dadd_rn((double)P1.y, 10.0), 0.1));
    bool inA = (ax >= 0.0) && (ax < (double)GW) && (ay >= 0.0) && (ay < (double)GH);
    bool inB = (bx >= 0.0) && (bx < (double)GW) && (by >= 0.0) && (by < (double)GH);
    if (!(inA || inB)) return;
    ax = fmin(fmax(ax, 0.0), (double)(GW - 1));
    ay = fmin(fmax(ay, 0.0), (double)(GH - 1));
    bx = fmin(fmax(bx, 0.0), (double)(GW - 1));
    by = fmin(fmax(by, 0.0), (double)(GH - 1));
    double dx = __dsub_rn(bx, ax);
    double dy = __dsub_rn(by, ay);
    double dmax = fmax(fabs(dx), fabs(dy));
    double denom = fmax(dmax, 1.0);
    int kmax = (int)dmax;
    for (int k = 0; k <= kmax; ++k) {
        double t = __ddiv_rn(fmin((double)k, dmax), denom);
        double ptx = __dadd_rn(ax, __dmul_rn(t, dx));
        double pty = __dadd_rn(ay, __dmul_rn(t, dy));
        int cx = (int)rint(ptx);  // half-to-even
        int cc = (int)rint(pty);
#pragma unroll
        for (int oy = -1; oy <= 1; ++oy) {
#pragma unroll
            for (int ox = -1; ox <= 1; ++ox) {
                int xx = cx + ox;
                int yy = cc + oy;
                if (xx < 0) xx += GW;  // JAX wraps negatives, drops OOB
                if (yy < 0) yy += GH;
                if (xx >= 0 && xx < GW && yy >= 0 && yy < GH) {
                    out_ch[yy * GW + xx] = 1.0f;
                }
            }
        }
    }
}

// ---------------------------------------------------------------------------
// P2b: blocks [0, T_TILES) reduce the S2 partials per cell (coalesced) and
// finalize; blocks [T_TILES,...) do polylines.
// ---------------------------------------------------------------------------
__global__ __launch_bounds__(256) void p2b_kernel(const unsigned* __restrict__ part_z,
                                                  const unsigned long long* __restrict__ part_ic,
                                                  float* __restrict__ out,
                                                  const float2* __restrict__ traj, int ntraj,
                                                  const float2* __restrict__ osm, int nosm,
                                                  const float* __restrict__ ego) {
    if (blockIdx.x >= T_TILES) {
        int seg = (blockIdx.x - T_TILES) * 256 + (int)threadIdx.x;
        do_poly_segment(seg, traj, ntraj, osm, nosm, ego, out);
        return;
    }
    int t = blockIdx.x;
    int l = threadIdx.x;
    size_t pbase = (size_t)t * S2 * 256;
    unsigned zfin = 0;
    unsigned long long v = 0;
#pragma unroll
    for (int s = 0; s < S2; ++s) {
        zfin = max(zfin, part_z[pbase + s * 256 + l]);  // coalesced across l
        v += part_ic[pbase + s * 256 + l];              // (cnt<<32)|sum merge-adds
    }
    int trow = t / TCOLS, tcol = t % TCOLS;
    int gy = trow * 16 + (l >> 4);
    int gx = tcol * 16 + (l & 15);
    if (gy < GH) {
        const float inv7 = 1.0f / 7.0f;
        const float invlog129 = 1.0f / 4.8598124043616719e+00f;  // 1/log(129)
        float h, ich, dd;
        if (v == 0) {
            h = fminf(fmaxf(__fmul_rn(3.0f, inv7), 0.0f), 1.0f);  // empty: clip(3/7)
            ich = 0.0f;
            dd = 0.0f;
        } else {
            unsigned cnt = (unsigned)(v >> 32);
            float sum8 = (float)(unsigned)(v & 0xFFFFFFFFull);  // exact (< 2^24 in fp path OK: <2^30, fp32 err negligible vs 2e-2)
            h = fminf((float)zfin * (1.0f / 65535.0f), 1.0f);   // z16-quantized h
            ich = fminf(__fdiv_rn(sum8, __fmul_rn((float)cnt, 255.0f)), 1.0f);
            dd = fminf(__fmul_rn(log1pf((float)cnt), invlog129), 1.0f);
        }
        int idx = gy * GW + gx;
        out[0 * GHW + idx] = h;
        out[1 * GHW + idx] = ich;
        out[2 * GHW + idx] = dd;
    }
}

// Standalone polyline kernel (fallback path).
__global__ __launch_bounds__(256) void polylines_kernel(const float2* __restrict__ traj,
                                                        int ntraj,
                                                        const float2* __restrict__ osm, int nosm,
                                                        const float* __restrict__ ego,
                                                        float* __restrict__ out) {
    int seg = blockIdx.x * 256 + (int)threadIdx.x;
    do_poly_segment(seg, traj, ntraj, osm, nosm, ego, out);
}

// ======================== fallback (round-3) path ==========================
__global__ __launch_bounds__(256) void init_kernel(float* __restrict__ out) {
    int i = blockIdx.x * blockDim.x + threadIdx.x;
    if (i < GHW) {
        out[0 * GHW + i] = -INFINITY;
        out[1 * GHW + i] = 0.0f;
        out[2 * GHW + i] = 0.0f;
        out[3 * GHW + i] = 0.0f;
        out[4 * GHW + i] = 0.0f;
    }
}

__device__ __forceinline__ void atomicMaxFloat(float* addr, float val) {
    if (val >= 0.0f) {
        atomicMax((int*)addr, __float_as_int(val));
    } else {
        atomicMin((unsigned int*)addr, (unsigned int)__float_as_int(val));
    }
}

__global__ __launch_bounds__(256) void lidar_kernel(const float4* __restrict__ pts, int n,
                                                    float* __restrict__ out) {
    int i = blockIdx.x * blockDim.x + threadIdx.x;
    if (i >= n) return;
    float4 p = pts[i];
    int px, py;
    if (!bin_point(p.x, p.y, px, py)) return;
    int idx = py * GW + px;
    atomicMaxFloat(&out[0 * GHW + idx], p.z);
    atomicAdd(&out[1 * GHW + idx], p.w);
    atomicAdd(&out[2 * GHW + idx], 1.0f);
}

__global__ __launch_bounds__(256) void finalize_kernel(float* __restrict__ out) {
    int i = blockIdx.x * blockDim.x + threadIdx.x;
    if (i >= GHW) return;
    float hm = out[0 * GHW + i];
    float isum = out[1 * GHW + i];
    float c = out[2 * GHW + i];
    if (hm == -INFINITY) hm = 0.0f;
    const float inv7 = 1.0f / 7.0f;
    const float inv255 = 1.0f / 255.0f;
    const float invlog129 = 1.0f / 4.8598124043616719e+00f;
    float h = fminf(fmaxf(__fmul_rn(__fadd_rn(hm, 3.0f), inv7), 0.0f), 1.0f);
    float im = (c > 0.0f) ? __fdiv_rn(isum, fmaxf(c, 1.0f)) : 0.0f;
    float ich = fminf(fmaxf(__fmul_rn(im, inv255), 0.0f), 1.0f);
    float dd = fminf(fmaxf(__fmul_rn(log1pf(c), invlog129), 0.0f), 1.0f);
    out[0 * GHW + i] = h;
    out[1 * GHW + i] = ich;
    out[2 * GHW + i] = dd;
}

extern "C" void kernel_launch(void* const* d_in, const int* in_sizes, int n_in,
                              void* d_out, int out_size, void* d_ws, size_t ws_size,
                              hipStream_t stream) {
    const float* lidar = (const float*)d_in[0];
    const float* traj = (const float*)d_in[1];
    const float* osm = (const float*)d_in[2];
    const float* ego = (const float*)d_in[3];
    float* out = (float*)d_out;

    int n_lidar = in_sizes[0] / 4;
    int n_traj = in_sizes[1] / 2;
    int n_osm = in_sizes[2] / 2;
    int nseg = (n_traj - 1) + (n_osm - 1);
    int npb = (nseg + 255) / 256;

    int per_block = (n_lidar + B1 - 1) / B1;
    size_t staged_bytes = (size_t)B1 * (size_t)per_block * 4;
    size_t pic_bytes = (size_t)T_TILES * S2 * 256 * 8;
    size_t pz_bytes = (size_t)T_TILES * S2 * 256 * 4;
    size_t pref_bytes = (size_t)(T_TILES + 1) * B1 * 4;
    size_t need = staged_bytes + pic_bytes + pz_bytes + pref_bytes;

    if (ws_size >= need && per_block <= 256 * Q) {
        char* w = (char*)d_ws;
        unsigned* staged = (unsigned*)w;
        unsigned long long* part_ic = (unsigned long long*)(w + staged_bytes);
        unsigned* part_z = (unsigned*)(w + staged_bytes + pic_bytes);
        unsigned* pref_t = (unsigned*)(w + staged_bytes + pic_bytes + pz_bytes);

        p1_kernel<<<B1, 256, 0, stream>>>((const float4*)lidar, n_lidar, per_block, staged,
                                          pref_t, out);
        p2a_kernel<<<T_TILES * S2, 256, 0, stream>>>(staged, pref_t, per_block, part_z, part_ic);
        p2b_kernel<<<T_TILES + npb, 256, 0, stream>>>(part_z, part_ic, out,
                                                      (const float2*)traj, n_traj,
                                                      (const float2*)osm, n_osm, ego);
    } else {
        // fallback: verified round-3 atomic path
        init_kernel<<<(GHW + 255) / 256, 256, 0, stream>>>(out);
        lidar_kernel<<<(n_lidar + 255) / 256, 256, 0, stream>>>((const float4*)lidar, n_lidar,
                                                                out);
        finalize_kernel<<<(GHW + 255) / 256, 256, 0, stream>>>(out);
        polylines_kernel<<<(nseg + 255) / 256, 256, 0, stream>>>((const float2*)traj, n_traj,
                                                                 (const float2*)osm, n_osm, ego,
                                                                 out);
    }
}